// Round 6
// baseline (585.979 us; speedup 1.0000x reference)
//
#include <hip/hip_runtime.h>
#include <hip/hip_bf16.h>

// FFB encoder, MI355X. Round 6: quad-split. Each 32-point group owned by 4
// waves (one 32-row h-tile each): buf 16 + acc 16 + X 32 regs -> <=128 regs
// -> 4 waves/SIMD. WG=512=2 quads, LDS 64KB (midhi stage 32K + X-exch 32K)
// -> 2 WGs/CU, 16 waves/CU. high-W + midlo frags direct from L2 (frag-linear),
// midhi staged in LDS (4x reuse). X handoff between quad waves via LDS exch,
// own chunks kept in regs. 2 barriers/level. Numerics identical to r5.

typedef __bf16 bf16_t;
typedef __attribute__((ext_vector_type(8))) __bf16 bf16x8;
typedef __attribute__((ext_vector_type(4))) float f32x4;
typedef __attribute__((ext_vector_type(16))) float f32x16;

#define C56R 8.9126768f               // 56 / (2*pi)
#define INV7 0.14285714285714285f

// ws layout (bytes) — r4 frag-linear layout, verified
#define OFF_WMF   0        // mid W hi, [7][4mt][8kc][64lane][8bf16]
#define OFF_WMFLO 229376   // mid W lo, same order
#define OFF_WHF   458752   // high W hi, same order
#define OFF_EPM   688128   // [7][2hf][4mt][16r] float4 {ap0, ap1, C56R*bm, C56R*bh}

union ChunkU { bf16x8 v; unsigned int d[4]; };

__device__ __forceinline__ unsigned short bfbits(float x) {
  bf16_t b = (bf16_t)x;
  return __builtin_bit_cast(unsigned short, b);
}
__device__ __forceinline__ float bf2f(unsigned short u) {
  return __builtin_bit_cast(float, (unsigned int)u << 16);
}
__device__ __forceinline__ void pack2(float v0, float v1,
                                      unsigned int& ph, unsigned int& pl) {
  unsigned short h0 = bfbits(v0), h1 = bfbits(v1);
  ph = (unsigned int)h0 | ((unsigned int)h1 << 16);
  float l0 = v0 - bf2f(h0), l1 = v1 - bf2f(h1);
  pl = (unsigned int)bfbits(l0) | ((unsigned int)bfbits(l1) << 16);
}
// 16 C-layout values (8 packed pairs) -> two B-layout chunks via half-wave
// exchange (values with (h mod 16) in 4..11 swap lane-halves). Verified r4/r5.
__device__ __forceinline__ void exch(const unsigned int P[8], int hf, int bpidx,
                                     ChunkU& cA, ChunkU& cB) {
  unsigned int t0 = hf ? P[0] : P[2];
  unsigned int t1 = hf ? P[1] : P[3];
  unsigned int t2 = hf ? P[4] : P[6];
  unsigned int t3 = hf ? P[5] : P[7];
  unsigned int r0 = (unsigned int)__builtin_amdgcn_ds_bpermute(bpidx, (int)t0);
  unsigned int r1 = (unsigned int)__builtin_amdgcn_ds_bpermute(bpidx, (int)t1);
  unsigned int r2 = (unsigned int)__builtin_amdgcn_ds_bpermute(bpidx, (int)t2);
  unsigned int r3 = (unsigned int)__builtin_amdgcn_ds_bpermute(bpidx, (int)t3);
  cA.d[0] = hf ? r0 : P[0];
  cA.d[1] = hf ? r1 : P[1];
  cA.d[2] = hf ? P[2] : r0;
  cA.d[3] = hf ? P[3] : r1;
  cB.d[0] = hf ? r2 : P[4];
  cB.d[1] = hf ? r3 : P[5];
  cB.d[2] = hf ? P[6] : r2;
  cB.d[3] = hf ? P[7] : r3;
}

__global__ void ffb_prep(const float* __restrict__ ffnA, const float* __restrict__ sigma,
                         const float* __restrict__ Wm, const float* __restrict__ bm,
                         const float* __restrict__ Wh, const float* __restrict__ bh,
                         unsigned char* __restrict__ ws) {
  int i = blockIdx.x * 256 + threadIdx.x;  // 448*256 = 114688 exactly
  bf16_t* wmf = (bf16_t*)(ws + OFF_WMF);
  bf16_t* wml = (bf16_t*)(ws + OFF_WMFLO);
  bf16_t* whf = (bf16_t*)(ws + OFF_WHF);
  {
    // fragment reorder: [it][mt][kc][lane][j]
    int j    = i & 7;
    int lane = (i >> 3) & 63;
    int kc   = (i >> 9) & 7;
    int mt   = (i >> 12) & 3;
    int it   = i >> 14;                       // 0..6
    int ho   = (mt << 5) + (lane & 31);
    int hin  = (kc << 4) + ((lane >> 5) << 3) + j;
    int src  = (it << 14) + (ho << 7) + hin;
    float w  = Wm[src];
    bf16_t h = (bf16_t)w;
    wmf[i] = h;
    wml[i] = (bf16_t)(w - (float)h);
    whf[i] = (bf16_t)Wh[src];
  }
  if (i < 896) {
    int r  = i & 15;
    int mt = (i >> 4) & 3;
    int hf = (i >> 6) & 1;
    int it = i >> 7;                          // 0..6
    int h  = (mt << 5) + (r & 3) + ((r >> 2) << 3) + (hf << 2);
    float sg = sigma[it];
    f32x4 e;
    e.x = ffnA[it * 256 + h] * sg;
    e.y = ffnA[it * 256 + 128 + h] * sg;
    e.z = C56R * bm[it * 128 + h];
    e.w = C56R * bh[it * 128 + h];
    ((f32x4*)(ws + OFF_EPM))[i] = e;
  }
}

__launch_bounds__(512, 4)
__global__ void ffb_main(const float* __restrict__ pos,
                         const float* __restrict__ gfeat,
                         const float* __restrict__ W0,
                         const float* __restrict__ b0,
                         const unsigned char* __restrict__ ws,
                         float* __restrict__ out) {
  // [0,32K): midhi stage; [32K,64K): X-exchange (2 quads x 16K)
  __shared__ __align__(16) unsigned char smem[65536];

  const int tid  = threadIdx.x;
  const int L    = tid & 63;
  const int wave = tid >> 6;        // 0..7
  const int qd   = wave >> 2;       // quad 0..1
  const int sub  = wave & 3;        // h-tile (mt) owned by this wave
  const int p    = L & 31;
  const int hf   = L >> 5;
  const int bpidx = (L ^ 32) << 2;
  const int n    = (blockIdx.x << 6) + (qd << 5) + p;

  const bf16_t* __restrict__ WML = (const bf16_t*)(ws + OFF_WMFLO);
  const bf16_t* __restrict__ WHF = (const bf16_t*)(ws + OFF_WHF);
  const f32x4*  __restrict__ EPM = (const f32x4*)(ws + OFF_EPM);
  const float*  __restrict__ EPW = (const float*)(ws + OFF_EPM);

  unsigned char* exb = smem + 32768 + (qd << 14);

  // stage level-0 midhi (32KB by 512 threads, 64B each)
  {
    const f32x4* src = (const f32x4*)(ws + OFF_WMF);
    f32x4* dst = (f32x4*)smem;
    #pragma unroll
    for (int c = 0; c < 4; ++c) dst[(tid << 2) + c] = src[(tid << 2) + c];
  }

  const float p0 = pos[n * 3 + 0], p1 = pos[n * 3 + 1], p2 = pos[n * 3 + 2];
  if (sub == 0 && hf == 0) {
    out[n * 131 + 0] = (p0 + 1.f) * 0.5f;
    out[n * 131 + 1] = (p1 + 1.f) * 0.5f;
    out[n * 131 + 2] = (p2 + 1.f) * 0.5f;
  }

  // ---- layer 0: x0 in B-layout chunks (all 4 quad waves compute full X).
  ChunkU xh[8], xl[8];
  #pragma unroll
  for (int cq = 0; cq < 8; ++cq) {
    #pragma unroll
    for (int jp = 0; jp < 4; ++jp) {
      int h0 = (cq << 4) + (hf << 3) + 2 * jp;
      float d0 = __builtin_fmaf(p2, W0[h0*3+2], __builtin_fmaf(p1, W0[h0*3+1], p0 * W0[h0*3+0]));
      float d1 = __builtin_fmaf(p2, W0[h0*3+5], __builtin_fmaf(p1, W0[h0*3+4], p0 * W0[h0*3+3]));
      float v0 = __builtin_amdgcn_sinf(C56R * (d0 + b0[h0]));
      float v1 = __builtin_amdgcn_sinf(C56R * (d1 + b0[h0 + 1]));
      pack2(v0, v1, xh[cq].d[jp], xl[cq].d[jp]);
    }
  }
  __syncthreads();   // level-0 midhi staged

  f32x16 buf;
  #pragma unroll
  for (int r = 0; r < 16; ++r) buf[r] = 0.f;

  for (int it = 0; it < 8; ++it) {
    // prefetch gfeat + next midhi stage data into regs (hide L2 latency)
    float g0 = 0.f, g1 = 0.f;
    if (it < 7) {
      g0 = gfeat[n * 17 + 3 + 2 * it];
      g1 = gfeat[n * 17 + 4 + 2 * it];
    }
    f32x4 sreg[4];
    if (it < 6) {
      const f32x4* src = (const f32x4*)(ws + OFF_WMF + (it + 1) * 32768);
      #pragma unroll
      for (int c = 0; c < 4; ++c) sreg[c] = src[(tid << 2) + c];
    }

    // ---- high pass: level it-1, frags direct from L2, 1 mt tile ----
    if (it > 0) {
      f32x16 acc;
      #pragma unroll
      for (int r = 0; r < 16; ++r) acc[r] = 0.f;
      const bf16_t* wb = WHF + ((it - 1) << 14) + (sub << 12) + (L << 3);
      #pragma unroll
      for (int kc = 0; kc < 8; ++kc) {
        bf16x8 f = *(const bf16x8*)(wb + (kc << 9));
        acc = __builtin_amdgcn_mfma_f32_32x32x16_bf16(f, xh[kc].v, acc, 0, 0, 0);
      }
      const int eb = ((((it - 1) << 1) + hf) << 2) + sub;
      #pragma unroll
      for (int r = 0; r < 16; ++r) {
        float cbh = EPW[(eb * 16 + r) * 4 + 3];
        buf[r] += __builtin_amdgcn_sinf(__builtin_fmaf(acc[r], C56R, cbh));
      }
    }

    // ---- mid pass: level it, midhi LDS + midlo L2, 1 mt tile ----
    if (it < 7) {
      f32x16 acc;
      #pragma unroll
      for (int r = 0; r < 16; ++r) acc[r] = 0.f;
      const bf16_t* sm = (const bf16_t*)smem + (sub << 12) + (L << 3);
      const bf16_t* wl = WML + (it << 14) + (sub << 12) + (L << 3);
      #pragma unroll
      for (int kc = 0; kc < 8; ++kc) {
        bf16x8 fh = *(const bf16x8*)(sm + (kc << 9));
        bf16x8 fl = *(const bf16x8*)(wl + (kc << 9));
        acc = __builtin_amdgcn_mfma_f32_32x32x16_bf16(fh, xh[kc].v, acc, 0, 0, 0);
        acc = __builtin_amdgcn_mfma_f32_32x32x16_bf16(fl, xh[kc].v, acc, 0, 0, 0);
        acc = __builtin_amdgcn_mfma_f32_32x32x16_bf16(fh, xl[kc].v, acc, 0, 0, 0);
      }
      // epilogue -> own two B-layout chunks (hi+lo)
      const int eb = (((it << 1) + hf) << 2) + sub;
      unsigned int Ph[8], Pl[8];
      #pragma unroll
      for (int rp = 0; rp < 8; ++rp) {
        f32x4 e0 = EPM[eb * 16 + 2 * rp];
        f32x4 e1 = EPM[eb * 16 + 2 * rp + 1];
        float sg0 = __builtin_amdgcn_sinf(__builtin_amdgcn_fractf(__builtin_fmaf(g1, e0.y, g0 * e0.x)));
        float sg1 = __builtin_amdgcn_sinf(__builtin_amdgcn_fractf(__builtin_fmaf(g1, e1.y, g0 * e1.x)));
        float sm0 = __builtin_amdgcn_sinf(__builtin_fmaf(acc[2*rp],   C56R, e0.z));
        float sm1 = __builtin_amdgcn_sinf(__builtin_fmaf(acc[2*rp+1], C56R, e1.z));
        pack2(sg0 + sm0, sg1 + sm1, Ph[rp], Pl[rp]);
      }
      ChunkU cAh, cBh, cAl, cBl;
      exch(Ph, hf, bpidx, cAh, cBh);
      exch(Pl, hf, bpidx, cAl, cBl);

      __syncthreads();   // B1: midhi reads + prev exch reads complete
      // stage next midhi (regs -> LDS) and publish own chunks
      if (it < 6) {
        f32x4* dst = (f32x4*)smem;
        #pragma unroll
        for (int c = 0; c < 4; ++c) dst[(tid << 2) + c] = sreg[c];
      }
      {
        const int cb = (sub << 1) * 2048 + (L << 4);
        *(bf16x8*)(exb + cb)        = cAh.v;
        *(bf16x8*)(exb + cb + 1024) = cAl.v;
        *(bf16x8*)(exb + cb + 2048) = cBh.v;
        *(bf16x8*)(exb + cb + 3072) = cBl.v;
      }
      __syncthreads();   // B2: stage + exchange visible
      // assemble X(it+1): own chunks from regs, others from LDS
      #pragma unroll
      for (int c = 0; c < 8; ++c) {
        if ((c >> 1) == sub) {
          xh[c] = (c & 1) ? cBh : cAh;
          xl[c] = (c & 1) ? cBl : cAl;
        } else {
          xh[c].v = *(const bf16x8*)(exb + c * 2048 + (L << 4));
          xl[c].v = *(const bf16x8*)(exb + c * 2048 + 1024 + (L << 4));
        }
      }
    }
  }

  // ---- final store: this wave's mt=sub rows for its 32 points.
  float* op = out + (size_t)n * 131 + 3;
  #pragma unroll
  for (int r = 0; r < 16; ++r) {
    const int h = (sub << 5) + (r & 3) + ((r >> 2) << 3) + (hf << 2);
    op[h] = buf[r] * INV7;
  }
}

extern "C" void kernel_launch(void* const* d_in, const int* in_sizes, int n_in,
                              void* d_out, int out_size, void* d_ws, size_t ws_size,
                              hipStream_t stream) {
  (void)in_sizes; (void)n_in; (void)out_size; (void)ws_size;
  const float* pos   = (const float*)d_in[0];
  const float* gfeat = (const float*)d_in[1];
  const float* ffnA  = (const float*)d_in[2];
  const float* sigma = (const float*)d_in[3];
  const float* W0    = (const float*)d_in[4];
  const float* b0    = (const float*)d_in[5];
  const float* Wm    = (const float*)d_in[6];
  const float* bm    = (const float*)d_in[7];
  const float* Wh    = (const float*)d_in[8];
  const float* bh    = (const float*)d_in[9];
  float* out = (float*)d_out;
  unsigned char* ws = (unsigned char*)d_ws;

  hipLaunchKernelGGL(ffb_prep, dim3(448), dim3(256), 0, stream,
                     ffnA, sigma, Wm, bm, Wh, bh, ws);
  hipLaunchKernelGGL(ffb_main, dim3(2048), dim3(512), 0, stream,
                     pos, gfeat, W0, b0, ws, out);
}

// Round 7
// 285.080 us; speedup vs baseline: 2.0555x; 2.0555x over previous
//
#include <hip/hip_runtime.h>
#include <hip/hip_bf16.h>

// FFB encoder, MI355X. Round 7: quad-split with X in LDS (B-frag layout).
// 4 waves per 32-point group, one 32-row h-tile each (acc 16 + buf 16 regs).
// X: per-quad LDS hi/lo in MFMA-B fragment order; mid epilogue writes new X
// straight to B-layout addresses (no bpermute exchange). MidHi W staged in
// LDS via async global_load_lds; high-W + midLo frags stream from L2.
// WG=512 (2 quads, 64 pts), LDS 64KB -> 2 WG/CU, 4 waves/EU @ <=128 regs.

typedef __bf16 bf16_t;
typedef __attribute__((ext_vector_type(8))) __bf16 bf16x8;
typedef __attribute__((ext_vector_type(4))) float f32x4;
typedef __attribute__((ext_vector_type(16))) float f32x16;

#define C56R 8.9126768f               // 56 / (2*pi)
#define INV7 0.14285714285714285f

// ws layout (bytes) — frag-linear, verified r4-r6
#define OFF_WMF   0        // mid W hi  [7][4mt][8kc][64lane][8bf16]
#define OFF_WMFLO 229376   // mid W lo
#define OFF_WHF   458752   // high W hi
#define OFF_EPM   688128   // [7][2hf][4mt][16r] float4 {ap0, ap1, C56R*bm, C56R*bh}

union ChunkU { bf16x8 v; unsigned int d[4]; };

__device__ __forceinline__ unsigned short bfbits(float x) {
  bf16_t b = (bf16_t)x;
  return __builtin_bit_cast(unsigned short, b);
}
__device__ __forceinline__ float bf2f(unsigned short u) {
  return __builtin_bit_cast(float, (unsigned int)u << 16);
}
__device__ __forceinline__ void pack2(float v0, float v1,
                                      unsigned int& ph, unsigned int& pl) {
  unsigned short h0 = bfbits(v0), h1 = bfbits(v1);
  ph = (unsigned int)h0 | ((unsigned int)h1 << 16);
  float l0 = v0 - bf2f(h0), l1 = v1 - bf2f(h1);
  pl = (unsigned int)bfbits(l0) | ((unsigned int)bfbits(l1) << 16);
}
// async global->LDS 16B per lane: dest = ldsbase + lane*16
__device__ __forceinline__ void stage16(const void* g, void* l) {
  __builtin_amdgcn_global_load_lds(
      (const __attribute__((address_space(1))) unsigned int*)g,
      (__attribute__((address_space(3))) unsigned int*)l, 16, 0, 0);
}

__global__ void ffb_prep(const float* __restrict__ ffnA, const float* __restrict__ sigma,
                         const float* __restrict__ Wm, const float* __restrict__ bm,
                         const float* __restrict__ Wh, const float* __restrict__ bh,
                         unsigned char* __restrict__ ws) {
  int i = blockIdx.x * 256 + threadIdx.x;  // 448*256 = 114688 exactly
  bf16_t* wmf = (bf16_t*)(ws + OFF_WMF);
  bf16_t* wml = (bf16_t*)(ws + OFF_WMFLO);
  bf16_t* whf = (bf16_t*)(ws + OFF_WHF);
  {
    // fragment reorder: [it][mt][kc][lane][j]
    int j    = i & 7;
    int lane = (i >> 3) & 63;
    int kc   = (i >> 9) & 7;
    int mt   = (i >> 12) & 3;
    int it   = i >> 14;                       // 0..6
    int ho   = (mt << 5) + (lane & 31);
    int hin  = (kc << 4) + ((lane >> 5) << 3) + j;
    int src  = (it << 14) + (ho << 7) + hin;
    float w  = Wm[src];
    bf16_t h = (bf16_t)w;
    wmf[i] = h;
    wml[i] = (bf16_t)(w - (float)h);
    whf[i] = (bf16_t)Wh[src];
  }
  if (i < 896) {
    int r  = i & 15;
    int mt = (i >> 4) & 3;
    int hf = (i >> 6) & 1;
    int it = i >> 7;                          // 0..6
    int h  = (mt << 5) + (r & 3) + ((r >> 2) << 3) + (hf << 2);
    float sg = sigma[it];
    f32x4 e;
    e.x = ffnA[it * 256 + h] * sg;
    e.y = ffnA[it * 256 + 128 + h] * sg;
    e.z = C56R * bm[it * 128 + h];
    e.w = C56R * bh[it * 128 + h];
    ((f32x4*)(ws + OFF_EPM))[i] = e;
  }
}

__launch_bounds__(512, 4)
__global__ void ffb_main(const float* __restrict__ pos,
                         const float* __restrict__ gfeat,
                         const float* __restrict__ W0,
                         const float* __restrict__ b0,
                         const unsigned char* __restrict__ ws,
                         float* __restrict__ out) {
  // [0,32K): midhi stage [mt][kc][64lane][16B]
  // [32K,64K): X per quad (16K each): hi [q8][64lane][16B], lo at +8192
  __shared__ __align__(16) unsigned char smem[65536];

  const int tid  = threadIdx.x;
  const int L    = tid & 63;
  const int wave = tid >> 6;        // 0..7
  const int qd   = wave >> 2;       // quad 0..1
  const int sub  = wave & 3;        // h-tile (mt) owned by this wave
  const int p    = L & 31;
  const int hf   = L >> 5;
  const int n    = (blockIdx.x << 6) + (qd << 5) + p;

  unsigned char* sMH = smem;
  unsigned char* sX  = smem + 32768 + (qd << 14);

  const bf16_t* __restrict__ WML = (const bf16_t*)(ws + OFF_WMFLO);
  const bf16_t* __restrict__ WHF = (const bf16_t*)(ws + OFF_WHF);
  const f32x4*  __restrict__ EPM = (const f32x4*)(ws + OFF_EPM);
  const float*  __restrict__ EPW = (const float*)(ws + OFF_EPM);

  // issue level-0 midhi stage: each wave 4 frags of 1024B
  {
    const unsigned char* src = ws + OFF_WMF + (wave << 12) + (L << 4);
    unsigned char* dst = sMH + (wave << 12);
    #pragma unroll
    for (int c = 0; c < 4; ++c)
      stage16(src + (c << 10), dst + (c << 10));
  }

  const float p0 = pos[n * 3 + 0], p1 = pos[n * 3 + 1], p2 = pos[n * 3 + 2];
  if (sub == 0 && hf == 0) {
    out[n * 131 + 0] = (p0 + 1.f) * 0.5f;
    out[n * 131 + 1] = (p1 + 1.f) * 0.5f;
    out[n * 131 + 2] = (p2 + 1.f) * 0.5f;
  }

  // ---- layer 0: each wave fills its 2 X chunks (B-frag layout) in LDS.
  #pragma unroll
  for (int cc = 0; cc < 2; ++cc) {
    const int c = (sub << 1) + cc;
    ChunkU chi, clo;
    #pragma unroll
    for (int jp = 0; jp < 4; ++jp) {
      int h0 = (c << 4) + (hf << 3) + 2 * jp;
      float d0 = __builtin_fmaf(p2, W0[h0*3+2], __builtin_fmaf(p1, W0[h0*3+1], p0 * W0[h0*3+0]));
      float d1 = __builtin_fmaf(p2, W0[h0*3+5], __builtin_fmaf(p1, W0[h0*3+4], p0 * W0[h0*3+3]));
      float v0 = __builtin_amdgcn_sinf(C56R * (d0 + b0[h0]));
      float v1 = __builtin_amdgcn_sinf(C56R * (d1 + b0[h0 + 1]));
      pack2(v0, v1, chi.d[jp], clo.d[jp]);
    }
    *(bf16x8*)(sX + (c << 10) + (L << 4))        = chi.v;
    *(bf16x8*)(sX + 8192 + (c << 10) + (L << 4)) = clo.v;
  }
  __syncthreads();   // X0 visible + level-0 midhi staged (vmcnt drained)

  f32x16 buf;
  #pragma unroll
  for (int r = 0; r < 16; ++r) buf[r] = 0.f;

  for (int it = 0; it < 8; ++it) {
    // ---- high pass: level it-1, W frags from L2 (prefetch-1), X-hi from LDS
    if (it > 0) {
      f32x16 acc;
      #pragma unroll
      for (int r = 0; r < 16; ++r) acc[r] = 0.f;
      const bf16_t* wb = WHF + ((it - 1) << 14) + (sub << 12) + (L << 3);
      bf16x8 fnext = *(const bf16x8*)(wb);
      #pragma unroll
      for (int kc = 0; kc < 8; ++kc) {
        bf16x8 f = fnext;
        if (kc < 7) fnext = *(const bf16x8*)(wb + ((kc + 1) << 9));
        bf16x8 xhc = *(const bf16x8*)(sX + (kc << 10) + (L << 4));
        acc = __builtin_amdgcn_mfma_f32_32x32x16_bf16(f, xhc, acc, 0, 0, 0);
      }
      const int eb = ((((it - 1) << 1) + hf) << 2) + sub;
      #pragma unroll
      for (int r = 0; r < 16; ++r) {
        float cbh = EPW[(eb * 16 + r) * 4 + 3];
        buf[r] += __builtin_amdgcn_sinf(__builtin_fmaf(acc[r], C56R, cbh));
      }
    }

    // ---- mid pass: level it ----
    if (it < 7) {
      f32x16 acc;
      #pragma unroll
      for (int r = 0; r < 16; ++r) acc[r] = 0.f;
      const bf16_t* wl = WML + (it << 14) + (sub << 12) + (L << 3);
      const unsigned char* smh = sMH + (sub << 13) + (L << 4);
      bf16x8 flnext = *(const bf16x8*)(wl);
      #pragma unroll
      for (int kc = 0; kc < 8; ++kc) {
        bf16x8 fl = flnext;
        if (kc < 7) flnext = *(const bf16x8*)(wl + ((kc + 1) << 9));
        bf16x8 fh  = *(const bf16x8*)(smh + (kc << 10));
        bf16x8 xhc = *(const bf16x8*)(sX + (kc << 10) + (L << 4));
        bf16x8 xlc = *(const bf16x8*)(sX + 8192 + (kc << 10) + (L << 4));
        acc = __builtin_amdgcn_mfma_f32_32x32x16_bf16(fh, xhc, acc, 0, 0, 0);
        acc = __builtin_amdgcn_mfma_f32_32x32x16_bf16(fl, xhc, acc, 0, 0, 0);
        acc = __builtin_amdgcn_mfma_f32_32x32x16_bf16(fh, xlc, acc, 0, 0, 0);
      }

      __syncthreads();   // B1: all reads of X(it) and midhi(it) complete

      // stage next level's midhi (async DMA, overlaps epilogue VALU)
      if (it < 6) {
        const unsigned char* src = ws + OFF_WMF + ((it + 1) << 15) + (wave << 12) + (L << 4);
        unsigned char* dst = sMH + (wave << 12);
        #pragma unroll
        for (int c = 0; c < 4; ++c)
          stage16(src + (c << 10), dst + (c << 10));
      }

      // epilogue: x(it+1) = sin(grid) + sin(56*mid+b); write to B-layout LDS
      const float g0 = gfeat[n * 17 + 3 + 2 * it];
      const float g1 = gfeat[n * 17 + 4 + 2 * it];
      const int eb = (((it << 1) + hf) << 2) + sub;
      #pragma unroll
      for (int rp = 0; rp < 8; ++rp) {
        const int r = 2 * rp;
        f32x4 e0 = EPM[eb * 16 + r];
        f32x4 e1 = EPM[eb * 16 + r + 1];
        float sg0 = __builtin_amdgcn_sinf(__builtin_amdgcn_fractf(__builtin_fmaf(g1, e0.y, g0 * e0.x)));
        float sg1 = __builtin_amdgcn_sinf(__builtin_amdgcn_fractf(__builtin_fmaf(g1, e1.y, g0 * e1.x)));
        float sm0 = __builtin_amdgcn_sinf(__builtin_fmaf(acc[r],     C56R, e0.z));
        float sm1 = __builtin_amdgcn_sinf(__builtin_fmaf(acc[r + 1], C56R, e1.z));
        unsigned int phv, plv;
        pack2(sg0 + sm0, sg1 + sm1, phv, plv);
        const int h   = (sub << 5) + (r & 3) + ((r >> 2) << 3) + (hf << 2);
        const int off = ((h >> 4) << 10) + ((p + (((h >> 3) & 1) << 5)) << 4) + ((h & 7) << 1);
        *(unsigned int*)(sX + off)        = phv;
        *(unsigned int*)(sX + 8192 + off) = plv;
      }
      __syncthreads();   // B2: X(it+1) + next midhi visible
    }
  }

  // ---- final store: this wave's mt=sub rows for its 32 points.
  float* op = out + (size_t)n * 131 + 3;
  #pragma unroll
  for (int r = 0; r < 16; ++r) {
    const int h = (sub << 5) + (r & 3) + ((r >> 2) << 3) + (hf << 2);
    op[h] = buf[r] * INV7;
  }
}

extern "C" void kernel_launch(void* const* d_in, const int* in_sizes, int n_in,
                              void* d_out, int out_size, void* d_ws, size_t ws_size,
                              hipStream_t stream) {
  (void)in_sizes; (void)n_in; (void)out_size; (void)ws_size;
  const float* pos   = (const float*)d_in[0];
  const float* gfeat = (const float*)d_in[1];
  const float* ffnA  = (const float*)d_in[2];
  const float* sigma = (const float*)d_in[3];
  const float* W0    = (const float*)d_in[4];
  const float* b0    = (const float*)d_in[5];
  const float* Wm    = (const float*)d_in[6];
  const float* bm    = (const float*)d_in[7];
  const float* Wh    = (const float*)d_in[8];
  const float* bh    = (const float*)d_in[9];
  float* out = (float*)d_out;
  unsigned char* ws = (unsigned char*)d_ws;

  hipLaunchKernelGGL(ffb_prep, dim3(448), dim3(256), 0, stream,
                     ffnA, sigma, Wm, bm, Wh, bh, ws);
  hipLaunchKernelGGL(ffb_main, dim3(2048), dim3(512), 0, stream,
                     pos, gfeat, W0, b0, ws, out);
}